// Round 5
// baseline (486.192 us; speedup 1.0000x reference)
//
#include <hip/hip_runtime.h>

#define HW 3136
#define C_ 256
#define T_ 8
#define NPOS 64
#define NBLK_PER_NT 49  // 3136/64
#define KP 352          // total nonzero taps = gathered K dimension (11*32)
#define NKS 11          // K-chunks of 32
#define FLAGBIT 0x40000000

typedef __attribute__((ext_vector_type(8))) short bf16x8;
typedef __attribute__((ext_vector_type(4))) float f32x4;
typedef __attribute__((ext_vector_type(4))) unsigned int u32x4;
typedef __attribute__((ext_vector_type(4))) int i32x4;

__device__ __forceinline__ unsigned int f2bf_u(float f) {
  unsigned int u = __float_as_uint(f);
  return (u + 0x7FFFu + ((u >> 16) & 1u)) >> 16;  // RNE; low 16 bits valid
}

// ws layout:
// [0,      180224): Wbp bf16 [256 oc][352 slots]   (Net[oc,c] * w_tap, folded)
// [180224, 181632): slotC  int[352]   (channel of each slot)
// [181632, 183040): slotW  float[352] (tap weight of each slot)
// [183040, 194304): rowtab int[8][352] (per-t x row element-offset | FLAGBIT if pad)

// ---- prep 1: extract taps, prefix-sum into slot list, build per-t row tables ----
__global__ void prep_table(const float* __restrict__ w1, const float* __restrict__ w3,
                           const float* __restrict__ w5, const float* __restrict__ w7,
                           int* __restrict__ slotC, float* __restrict__ slotW,
                           int* __restrict__ rowtab) {
  const int c = threadIdx.x;  // one block, 256 threads
  for (int s = c; s < KP; s += 256) {
    slotC[s] = 0;
    slotW[s] = 0.f;
    for (int t = 0; t < T_; ++t) rowtab[t * KP + s] = 0;
  }
  const int g = c >> 6, lc = c & 63, K = 2 * g + 1;
  const float* wsrc = (g == 0) ? w1 : (g == 1) ? w3 : (g == 2) ? w5 : w7;
  float w[3] = {0.f, 0.f, 0.f};
  int d[3] = {0, 0, 0};
  int cnt = 0;
  for (int k = 0; k < K && cnt < 3; ++k) {
    float v = wsrc[lc * K + k];
    if (v != 0.0f) { w[cnt] = v; d[cnt] = k - g; ++cnt; }
  }
  __shared__ int ps[256];
  ps[c] = cnt;
  __syncthreads();
  for (int dlt = 1; dlt < 256; dlt <<= 1) {  // inclusive scan (Hillis-Steele)
    int v = (c >= dlt) ? ps[c - dlt] : 0;
    __syncthreads();
    ps[c] += v;
    __syncthreads();
  }
  const int off = ps[c] - cnt;
  for (int i = 0; i < cnt; ++i) {
    const int s = off + i;
    if (s >= KP) break;
    slotC[s] = c;
    slotW[s] = w[i];
    for (int t = 0; t < T_; ++t) {
      const int tq = t + d[i];
      const bool valid = (unsigned)tq < (unsigned)T_;
      const int tqc = valid ? tq : (tq < 0 ? 0 : T_ - 1);
      rowtab[t * KP + s] = ((tqc * C_ + c) * HW) | (valid ? 0 : FLAGBIT);
    }
  }
}

// ---- prep 2: Wbp[oc][s] = bf16(net_w[oc, slotC[s]] * slotW[s]) ----
__global__ void prep_wb(const float* __restrict__ net_w, const int* __restrict__ slotC,
                        const float* __restrict__ slotW, unsigned short* __restrict__ Wbp) {
  const int oc = blockIdx.x;
  const int s = threadIdx.x;
  if (s < KP) Wbp[oc * KP + s] = (unsigned short)f2bf_u(net_w[oc * C_ + slotC[s]] * slotW[s]);
}

// Wave-autonomous fused kernel: NO inter-wave LDS sharing, NO K-loop barriers.
// Block = 512 threads = 8 waves over one (nt, 64-pos tile).
//   wave w: oc quad (w&3)*64, pos half (w>>2)*32.
// Each wave loads its B fragments straight from global in MFMA layout:
//   inst (j, ni): lane(m16,quad) <- x[row(quad*8+j)][p0+ph*32+ni*16+m16]
//   => 4 x 64B fully-used segments per inst, L1 dedupes across waves.
__global__ __launch_bounds__(512, 4) void fused_kernel(
    const float* __restrict__ x, const unsigned short* __restrict__ Wbp,
    const int* __restrict__ rowtab, float* __restrict__ out) {
  const int blk = blockIdx.x;
  const int nt = blk / NBLK_PER_NT;
  const int p0 = (blk % NBLK_PER_NT) * NPOS;
  const int n = nt >> 3, t = nt & 7;
  const int tid = threadIdx.x;
  const int lane = tid & 63;
  const int wv = tid >> 6;
  const int m16 = lane & 15;
  const int quad = lane >> 4;
  const int ocq = wv & 3;   // oc quadrant: [ocq*64, ocq*64+64)
  const int ph = wv >> 2;   // pos half: [ph*32, ph*32+32)

  __shared__ __align__(16) int ltab[KP];  // row table only (1.4 KiB)
  for (int i = tid; i < KP; i += 512) ltab[i] = rowtab[t * KP + i];

  f32x4 acc[4][2];
#pragma unroll
  for (int i = 0; i < 4; ++i)
#pragma unroll
    for (int j = 0; j < 2; ++j) acc[i][j] = (f32x4){0.f, 0.f, 0.f, 0.f};

  // per-lane bases
  const float* xpos = x + (size_t)(n * 8) * C_ * HW + (size_t)(p0 + ph * 32 + m16);
  const unsigned short* wb = Wbp + (ocq * 64 + m16) * KP + quad * 8;

  __syncthreads();  // ltab ready; the ONLY block-wide barrier

// gathered B-fragment loads for chunk KS -> xv[P][8 rows][2 ni]; pad flags -> fm[P]
#define LOADX(KS, P)                                                   \
  do {                                                                 \
    const i32x4 ro0 = *(const i32x4*)&ltab[(KS) * 32 + quad * 8];      \
    const i32x4 ro1 = *(const i32x4*)&ltab[(KS) * 32 + quad * 8 + 4];  \
    int fm_ = 0;                                                       \
    _Pragma("unroll") for (int j = 0; j < 4; ++j) {                    \
      const float* rpa = xpos + (ro0[j] & (FLAGBIT - 1));              \
      const float* rpb = xpos + (ro1[j] & (FLAGBIT - 1));              \
      _Pragma("unroll") for (int ni = 0; ni < 2; ++ni) {               \
        xv[P][j][ni] = rpa[ni * 16];                                   \
        xv[P][4 + j][ni] = rpb[ni * 16];                               \
      }                                                                \
      fm_ |= ((ro0[j] >> 30) & 1) << j;                                \
      fm_ |= ((ro1[j] >> 30) & 1) << (4 + j);                          \
    }                                                                  \
    fm[P] = fm_;                                                       \
  } while (0)

// A fragments for chunk KS (single-buffered; issued right after previous MFMA)
#define LOADAF(KS)                                                     \
  do {                                                                 \
    _Pragma("unroll") for (int mi = 0; mi < 4; ++mi)                   \
      afr[mi] = *(const bf16x8*)&wb[mi * 16 * KP + (KS) * 32];         \
  } while (0)

// pack xv[P] (mask pads) -> bfrags, MFMA into acc
#define PACKMFMA(P)                                                    \
  do {                                                                 \
    unsigned int msk[8];                                               \
    _Pragma("unroll") for (int j = 0; j < 8; ++j)                      \
      msk[j] = ((unsigned int)((fm[P] >> j) & 1)) - 1u;                \
    _Pragma("unroll") for (int ni = 0; ni < 2; ++ni) {                 \
      u32x4 bd;                                                        \
      _Pragma("unroll") for (int d2 = 0; d2 < 4; ++d2) {               \
        const unsigned int lo =                                        \
            f2bf_u(__uint_as_float(__float_as_uint(xv[P][2 * d2][ni]) & msk[2 * d2]));  \
        const unsigned int hi =                                        \
            f2bf_u(__uint_as_float(__float_as_uint(xv[P][2 * d2 + 1][ni]) & msk[2 * d2 + 1])); \
        bd[d2] = (lo & 0xFFFFu) | (hi << 16);                          \
      }                                                                \
      const bf16x8 bfrag = *(const bf16x8*)&bd;                        \
      _Pragma("unroll") for (int mi = 0; mi < 4; ++mi)                 \
        acc[mi][ni] = __builtin_amdgcn_mfma_f32_16x16x32_bf16(afr[mi], bfrag, \
                                                              acc[mi][ni], 0, 0, 0); \
    }                                                                  \
  } while (0)

  float xv[2][8][2];
  int fm[2];
  bf16x8 afr[4];

  // prologue
  LOADX(0, 0);
  LOADAF(0);

#pragma unroll
  for (int ks = 0; ks < NKS; ++ks) {
    // issue next chunk's B loads first: load->use distance = one full iteration
    if (ks + 1 < NKS) LOADX(ks + 1, (ks + 1) & 1);
    __builtin_amdgcn_sched_barrier(0);
    PACKMFMA(ks & 1);  // waits only chunk ks's loads; ks+1 stays in flight
    if (ks + 1 < NKS) LOADAF(ks + 1);  // afr regs freed by the MFMAs above
    __builtin_amdgcn_sched_barrier(0);
  }
#undef LOADX
#undef LOADAF
#undef PACKMFMA

  // ---- epilogue: D row(oc) = quad*4 + reg, col(pos) = m16 ----
  const size_t obase = (size_t)nt * C_ * HW + p0 + ph * 32 + m16;
#pragma unroll
  for (int mi = 0; mi < 4; ++mi) {
#pragma unroll
    for (int r = 0; r < 4; ++r) {
      const int oc = ocq * 64 + mi * 16 + quad * 4 + r;
      float* orow = out + obase + (size_t)oc * HW;
#pragma unroll
      for (int ni = 0; ni < 2; ++ni) orow[ni * 16] = acc[mi][ni][r];
    }
  }
}

extern "C" void kernel_launch(void* const* d_in, const int* in_sizes, int n_in,
                              void* d_out, int out_size, void* d_ws, size_t ws_size,
                              hipStream_t stream) {
  const float* x = (const float*)d_in[0];
  const float* w1 = (const float*)d_in[1];
  const float* w3 = (const float*)d_in[2];
  const float* w5 = (const float*)d_in[3];
  const float* w7 = (const float*)d_in[4];
  const float* net_w = (const float*)d_in[5];
  float* out = (float*)d_out;

  char* ws = (char*)d_ws;
  unsigned short* Wbp = (unsigned short*)ws;
  int* slotC = (int*)(ws + 180224);
  float* slotW = (float*)(ws + 181632);
  int* rowtab = (int*)(ws + 183040);

  hipLaunchKernelGGL(prep_table, dim3(1), dim3(256), 0, stream, w1, w3, w5, w7,
                     slotC, slotW, rowtab);
  hipLaunchKernelGGL(prep_wb, dim3(C_), dim3(384), 0, stream, net_w, slotC, slotW, Wbp);
  hipLaunchKernelGGL(fused_kernel, dim3(64 * NBLK_PER_NT), dim3(512), 0, stream,
                     x, Wbp, rowtab, out);
}